// Round 7
// baseline (420.581 us; speedup 1.0000x reference)
//
#include <hip/hip_runtime.h>

#define D 128
#define SCAN_B 256
#define BM 32
#define BK 32
#define HS_LD 132

// ---- degree count ----
__global__ void count_kernel(const int* __restrict__ ei, int E, int* __restrict__ cnt) {
    int t = blockIdx.x * blockDim.x + threadIdx.x;
    if (t < E) atomicAdd(&cnt[ei[E + t]], 1);
}

// ---- hierarchical exclusive scan ----
__global__ void scan_pass1(const int* __restrict__ cnt, int* __restrict__ rs,
                           int* __restrict__ bsum, int N) {
    __shared__ int lds[SCAN_B];
    int tid = threadIdx.x;
    int i = blockIdx.x * SCAN_B + tid;
    int v = (i < N) ? cnt[i] : 0;
    lds[tid] = v;
    __syncthreads();
    for (int o = 1; o < SCAN_B; o <<= 1) {
        int t = (tid >= o) ? lds[tid - o] : 0;
        __syncthreads();
        lds[tid] += t;
        __syncthreads();
    }
    if (i < N) rs[i] = lds[tid] - v;
    if (tid == SCAN_B - 1) bsum[blockIdx.x] = lds[tid];
}

__global__ void scan_pass2(int* __restrict__ bsum, int nb) {
    __shared__ int lds[SCAN_B];
    int tid = threadIdx.x;
    int v = (tid < nb) ? bsum[tid] : 0;
    lds[tid] = v;
    __syncthreads();
    for (int o = 1; o < SCAN_B; o <<= 1) {
        int t = (tid >= o) ? lds[tid - o] : 0;
        __syncthreads();
        lds[tid] += t;
        __syncthreads();
    }
    if (tid < nb) bsum[tid] = lds[tid] - v;
}

// scan finalize + inv (fused)
__global__ void scan_pass3(int* __restrict__ rs, int* __restrict__ cursor,
                           const int* __restrict__ bsum, const int* __restrict__ cnt,
                           float* __restrict__ inv, int N) {
    int i = blockIdx.x * SCAN_B + threadIdx.x;
    if (i < N) {
        int v = rs[i] + bsum[blockIdx.x];
        rs[i] = v;
        cursor[i] = v;
        inv[i] = 1.0f / (float)max(cnt[i], 1);
    }
}

__global__ void fill_kernel(const int* __restrict__ ei, int E,
                            int* __restrict__ cursor, int* __restrict__ csr) {
    int e = blockIdx.x * blockDim.x + threadIdx.x;
    if (e < E) {
        int src = ei[e], dst = ei[E + e];
        int pos = atomicAdd(&cursor[dst], 1);
        csr[pos] = src;
    }
}

// ---- gather-mean aggregate: 32 lanes per node, 8-way unrolled ----
__global__ void aggregate_kernel(const float* __restrict__ x, const int* __restrict__ csr,
                                 const int* __restrict__ rs, const int* __restrict__ cnt,
                                 const float* __restrict__ inv, float* __restrict__ agg,
                                 int N) {
    int t = blockIdx.x * blockDim.x + threadIdx.x;
    int node = t >> 5;
    int c = t & 31;
    if (node >= N) return;
    int deg = cnt[node];
    int st = rs[node];
    const float4* x4 = (const float4*)x;
    float4 s0 = make_float4(0.f, 0.f, 0.f, 0.f);
    float4 s1 = make_float4(0.f, 0.f, 0.f, 0.f);
    int i = 0;
    for (; i + 8 <= deg; i += 8) {
        int n0 = csr[st + i + 0], n1 = csr[st + i + 1];
        int n2 = csr[st + i + 2], n3 = csr[st + i + 3];
        int n4 = csr[st + i + 4], n5 = csr[st + i + 5];
        int n6 = csr[st + i + 6], n7 = csr[st + i + 7];
        float4 v0 = x4[(size_t)n0 * 32 + c];
        float4 v1 = x4[(size_t)n1 * 32 + c];
        float4 v2 = x4[(size_t)n2 * 32 + c];
        float4 v3 = x4[(size_t)n3 * 32 + c];
        float4 v4 = x4[(size_t)n4 * 32 + c];
        float4 v5 = x4[(size_t)n5 * 32 + c];
        float4 v6 = x4[(size_t)n6 * 32 + c];
        float4 v7 = x4[(size_t)n7 * 32 + c];
        s0.x += (v0.x + v1.x) + (v2.x + v3.x);
        s0.y += (v0.y + v1.y) + (v2.y + v3.y);
        s0.z += (v0.z + v1.z) + (v2.z + v3.z);
        s0.w += (v0.w + v1.w) + (v2.w + v3.w);
        s1.x += (v4.x + v5.x) + (v6.x + v7.x);
        s1.y += (v4.y + v5.y) + (v6.y + v7.y);
        s1.z += (v4.z + v5.z) + (v6.z + v7.z);
        s1.w += (v4.w + v5.w) + (v6.w + v7.w);
    }
    for (; i + 4 <= deg; i += 4) {
        int n0 = csr[st + i + 0], n1 = csr[st + i + 1];
        int n2 = csr[st + i + 2], n3 = csr[st + i + 3];
        float4 v0 = x4[(size_t)n0 * 32 + c];
        float4 v1 = x4[(size_t)n1 * 32 + c];
        float4 v2 = x4[(size_t)n2 * 32 + c];
        float4 v3 = x4[(size_t)n3 * 32 + c];
        s0.x += v0.x + v1.x; s0.y += v0.y + v1.y;
        s0.z += v0.z + v1.z; s0.w += v0.w + v1.w;
        s1.x += v2.x + v3.x; s1.y += v2.y + v3.y;
        s1.z += v2.z + v3.z; s1.w += v2.w + v3.w;
    }
    for (; i < deg; i++) {
        int n0 = csr[st + i];
        float4 v0 = x4[(size_t)n0 * 32 + c];
        s0.x += v0.x; s0.y += v0.y; s0.z += v0.z; s0.w += v0.w;
    }
    float iv = inv[node];
    float4 s = make_float4((s0.x + s1.x) * iv, (s0.y + s1.y) * iv,
                           (s0.z + s1.z) * iv, (s0.w + s1.w) * iv);
    ((float4*)agg)[(size_t)node * 32 + c] = s;
}

// ---- register-prefetch pipelined GEMM, BM=32, thread tile 4x4 ----
// C[32 x 128] = relu(l2norm([agg|x] @ [Wl;Wr] + bl)) [@ Wf + bf]
// 256 threads: tg=tid>>5 -> 4 nodes, tn=tid&31 -> 4 cols
template <int FUSE_FC>
__global__ __launch_bounds__(256) void gemm_kernel(
        const float* __restrict__ agg, const float* __restrict__ x,
        const float* __restrict__ Wl, const float* __restrict__ bl,
        const float* __restrict__ Wr,
        const float* __restrict__ Wf, const float* __restrict__ bf,
        float* __restrict__ out, int N) {
    // smem: As[32][32]=1024f | Ws[32][128]=4096f -> 20480B
    // FC's Hs[32][132]=4224f overlaps (<= 5120f)
    __shared__ float smem[BM * BK + BK * D];
    float* As = smem;
    float* Ws = smem + BM * BK;

    const int tid = threadIdx.x;
    const int tn = tid & 31;
    const int tg = tid >> 5;
    const int m_base = tg * 4;
    const int n_base = tn * 4;
    const int mb = blockIdx.x * BM;

    // staging coords
    const int m_st = tid >> 3;        // 0..31
    const int kq   = tid & 7;         // 0..7  (float4 within 32-K row)
    int ngA = mb + m_st;
    if (ngA >= N) ngA = N - 1;
    const size_t a_row = (size_t)ngA * 32;

    float acc[4][4];
#pragma unroll
    for (int i = 0; i < 4; i++)
#pragma unroll
        for (int j = 0; j < 4; j++) acc[i][j] = 0.0f;

    // prefetch tile 0 into registers
    float4 pa = ((const float4*)agg)[a_row + kq];
    float4 pw[4];
#pragma unroll
    for (int r = 0; r < 4; r++)
        pw[r] = ((const float4*)Wl)[(size_t)(tg + 8 * r) * 32 + tn];

    for (int kk = 0; kk < 2 * D; kk += BK) {
        // store prefetched tile to LDS
        *((float4*)&As[m_st * BK + kq * 4]) = pa;
#pragma unroll
        for (int r = 0; r < 4; r++)
            ((float4*)Ws)[(tg + 8 * r) * 32 + tn] = pw[r];
        __syncthreads();

        // issue next tile's global loads (latency hidden behind compute)
        int kn = kk + BK;
        if (kn < 2 * D) {
            const float* Ab = (kn < D) ? agg : x;
            const float* Wb = (kn < D) ? Wl : Wr;
            const int kl = kn & (D - 1);
            pa = ((const float4*)Ab)[a_row + (kl >> 2) + kq];
#pragma unroll
            for (int r = 0; r < 4; r++)
                pw[r] = ((const float4*)Wb)[(size_t)(kl + tg + 8 * r) * 32 + tn];
        }

        // compute on current tile
#pragma unroll
        for (int k4 = 0; k4 < BK / 4; k4++) {
            float4 w0 = *((const float4*)&Ws[(k4 * 4 + 0) * D + n_base]);
            float4 w1 = *((const float4*)&Ws[(k4 * 4 + 1) * D + n_base]);
            float4 w2 = *((const float4*)&Ws[(k4 * 4 + 2) * D + n_base]);
            float4 w3 = *((const float4*)&Ws[(k4 * 4 + 3) * D + n_base]);
#pragma unroll
            for (int mi = 0; mi < 4; mi++) {
                float4 a = *((const float4*)&As[(m_base + mi) * BK + k4 * 4]);
                acc[mi][0] = fmaf(a.x, w0.x, acc[mi][0]);
                acc[mi][1] = fmaf(a.x, w0.y, acc[mi][1]);
                acc[mi][2] = fmaf(a.x, w0.z, acc[mi][2]);
                acc[mi][3] = fmaf(a.x, w0.w, acc[mi][3]);
                acc[mi][0] = fmaf(a.y, w1.x, acc[mi][0]);
                acc[mi][1] = fmaf(a.y, w1.y, acc[mi][1]);
                acc[mi][2] = fmaf(a.y, w1.z, acc[mi][2]);
                acc[mi][3] = fmaf(a.y, w1.w, acc[mi][3]);
                acc[mi][0] = fmaf(a.z, w2.x, acc[mi][0]);
                acc[mi][1] = fmaf(a.z, w2.y, acc[mi][1]);
                acc[mi][2] = fmaf(a.z, w2.z, acc[mi][2]);
                acc[mi][3] = fmaf(a.z, w2.w, acc[mi][3]);
                acc[mi][0] = fmaf(a.w, w3.x, acc[mi][0]);
                acc[mi][1] = fmaf(a.w, w3.y, acc[mi][1]);
                acc[mi][2] = fmaf(a.w, w3.z, acc[mi][2]);
                acc[mi][3] = fmaf(a.w, w3.w, acc[mi][3]);
            }
        }
        __syncthreads();
    }

    // epilogue: bias + per-node L2 norm (32-lane reduction) + relu
    const float4 blv = ((const float4*)bl)[tn];
    float h[4][4];
#pragma unroll
    for (int mi = 0; mi < 4; mi++) {
        float v0 = acc[mi][0] + blv.x;
        float v1 = acc[mi][1] + blv.y;
        float v2 = acc[mi][2] + blv.z;
        float v3 = acc[mi][3] + blv.w;
        float s = v0 * v0 + v1 * v1 + v2 * v2 + v3 * v3;
#pragma unroll
        for (int o = 16; o > 0; o >>= 1) s += __shfl_xor(s, o, 32);
        float rn = 1.0f / fmaxf(sqrtf(s), 1e-12f);
        h[mi][0] = fmaxf(v0 * rn, 0.0f);
        h[mi][1] = fmaxf(v1 * rn, 0.0f);
        h[mi][2] = fmaxf(v2 * rn, 0.0f);
        h[mi][3] = fmaxf(v3 * rn, 0.0f);
    }

    if (!FUSE_FC) {
#pragma unroll
        for (int mi = 0; mi < 4; mi++) {
            int node = mb + m_base + mi;
            if (node < N) {
                float4 o4 = make_float4(h[mi][0], h[mi][1], h[mi][2], h[mi][3]);
                ((float4*)out)[(size_t)node * 32 + tn] = o4;
            }
        }
        return;
    }

    // FC: Hs reuses smem; Wf streamed from global (L1/L2-hot).
    float* Hs = smem;  // [32][HS_LD], HS_LD=132 >= 128 + pad
#pragma unroll
    for (int mi = 0; mi < 4; mi++) {
        float4 o4 = make_float4(h[mi][0], h[mi][1], h[mi][2], h[mi][3]);
        *((float4*)&Hs[(m_base + mi) * HS_LD + n_base]) = o4;
    }
    __syncthreads();

    const float4 bfv = ((const float4*)bf)[tn];
    float acc2[4][4];
#pragma unroll
    for (int mi = 0; mi < 4; mi++) {
        acc2[mi][0] = bfv.x; acc2[mi][1] = bfv.y;
        acc2[mi][2] = bfv.z; acc2[mi][3] = bfv.w;
    }

#pragma unroll 4
    for (int k4 = 0; k4 < D / 4; k4++) {
        float4 w0 = ((const float4*)Wf)[(size_t)(k4 * 4 + 0) * 32 + tn];
        float4 w1 = ((const float4*)Wf)[(size_t)(k4 * 4 + 1) * 32 + tn];
        float4 w2 = ((const float4*)Wf)[(size_t)(k4 * 4 + 2) * 32 + tn];
        float4 w3 = ((const float4*)Wf)[(size_t)(k4 * 4 + 3) * 32 + tn];
#pragma unroll
        for (int mi = 0; mi < 4; mi++) {
            float4 a = *((const float4*)&Hs[(m_base + mi) * HS_LD + k4 * 4]);
            acc2[mi][0] = fmaf(a.x, w0.x, acc2[mi][0]);
            acc2[mi][1] = fmaf(a.x, w0.y, acc2[mi][1]);
            acc2[mi][2] = fmaf(a.x, w0.z, acc2[mi][2]);
            acc2[mi][3] = fmaf(a.x, w0.w, acc2[mi][3]);
            acc2[mi][0] = fmaf(a.y, w1.x, acc2[mi][0]);
            acc2[mi][1] = fmaf(a.y, w1.y, acc2[mi][1]);
            acc2[mi][2] = fmaf(a.y, w1.z, acc2[mi][2]);
            acc2[mi][3] = fmaf(a.y, w1.w, acc2[mi][3]);
            acc2[mi][0] = fmaf(a.z, w2.x, acc2[mi][0]);
            acc2[mi][1] = fmaf(a.z, w2.y, acc2[mi][1]);
            acc2[mi][2] = fmaf(a.z, w2.z, acc2[mi][2]);
            acc2[mi][3] = fmaf(a.z, w2.w, acc2[mi][3]);
            acc2[mi][0] = fmaf(a.w, w3.x, acc2[mi][0]);
            acc2[mi][1] = fmaf(a.w, w3.y, acc2[mi][1]);
            acc2[mi][2] = fmaf(a.w, w3.z, acc2[mi][2]);
            acc2[mi][3] = fmaf(a.w, w3.w, acc2[mi][3]);
        }
    }

#pragma unroll
    for (int mi = 0; mi < 4; mi++) {
        int node = mb + m_base + mi;
        if (node < N) {
            float4 o4 = make_float4(acc2[mi][0], acc2[mi][1], acc2[mi][2], acc2[mi][3]);
            ((float4*)out)[(size_t)node * 32 + tn] = o4;
        }
    }
}

extern "C" void kernel_launch(void* const* d_in, const int* in_sizes, int n_in,
                              void* d_out, int out_size, void* d_ws, size_t ws_size,
                              hipStream_t stream) {
    const float* x   = (const float*)d_in[0];
    const int*   ei  = (const int*)d_in[1];
    const float* W1l = (const float*)d_in[2];
    const float* b1  = (const float*)d_in[3];
    const float* W1r = (const float*)d_in[4];
    const float* W2l = (const float*)d_in[5];
    const float* b2  = (const float*)d_in[6];
    const float* W2r = (const float*)d_in[7];
    const float* Wf  = (const float*)d_in[8];
    const float* bf  = (const float*)d_in[9];
    float* out = (float*)d_out;

    int N = in_sizes[0] / D;
    int E = in_sizes[1] / 2;

    // ws layout: agg[N*D] f | inv[N] f | rs[N] i | cnt[N] i | cursor[N] i | bsum[256] i | csr[E] i
    float* ws     = (float*)d_ws;
    float* agg    = ws;
    float* inv    = ws + (size_t)N * D;
    int*   rs     = (int*)(inv + N);
    int*   cnt    = rs + N;
    int*   cursor = cnt + N;
    int*   bsum   = cursor + N;
    int*   csr    = bsum + 256;

    int nb = (N + SCAN_B - 1) / SCAN_B;

    hipMemsetAsync(cnt, 0, (size_t)N * sizeof(int), stream);
    count_kernel<<<(E + 255) / 256, 256, 0, stream>>>(ei, E, cnt);
    scan_pass1<<<nb, SCAN_B, 0, stream>>>(cnt, rs, bsum, N);
    scan_pass2<<<1, SCAN_B, 0, stream>>>(bsum, nb);
    scan_pass3<<<nb, SCAN_B, 0, stream>>>(rs, cursor, bsum, cnt, inv, N);
    fill_kernel<<<(E + 255) / 256, 256, 0, stream>>>(ei, E, cursor, csr);

    int agg_blocks = (N * 32 + 255) / 256;
    int gemm_blocks = (N + BM - 1) / BM;

    // layer 1 (h1 lives in d_out)
    aggregate_kernel<<<agg_blocks, 256, 0, stream>>>(x, csr, rs, cnt, inv, agg, N);
    gemm_kernel<0><<<gemm_blocks, 256, 0, stream>>>(agg, x, W1l, b1, W1r,
                                                    nullptr, nullptr, out, N);

    // layer 2 + fused final fc (reads h1 from d_out, overwrites d_out)
    aggregate_kernel<<<agg_blocks, 256, 0, stream>>>(out, csr, rs, cnt, inv, agg, N);
    gemm_kernel<1><<<gemm_blocks, 256, 0, stream>>>(agg, out, W2l, b2, W2r,
                                                    Wf, bf, out, N);
}

// Round 8
// 312.751 us; speedup vs baseline: 1.3448x; 1.3448x over previous
//
#include <hip/hip_runtime.h>

#define D 128
#define SCAN_B 256
#define AS_LD 36   // 64-row fp32 A tile, padded stride (bank-spread)

typedef __attribute__((ext_vector_type(8))) short bf16x8;
typedef __attribute__((ext_vector_type(4))) float f32x4;

__device__ __forceinline__ unsigned short f2bf(float f) {
    unsigned u = __float_as_uint(f);
    unsigned r = u + 0x7FFFu + ((u >> 16) & 1u);  // RNE
    return (unsigned short)(r >> 16);
}
__device__ __forceinline__ float bf2f(unsigned short h) {
    return __uint_as_float(((unsigned)h) << 16);
}

// ---- degree count ----
__global__ void count_kernel(const int* __restrict__ ei, int E, int* __restrict__ cnt) {
    int t = blockIdx.x * blockDim.x + threadIdx.x;
    if (t < E) atomicAdd(&cnt[ei[E + t]], 1);
}

// ---- hierarchical exclusive scan ----
__global__ void scan_pass1(const int* __restrict__ cnt, int* __restrict__ rs,
                           int* __restrict__ bsum, int N) {
    __shared__ int lds[SCAN_B];
    int tid = threadIdx.x;
    int i = blockIdx.x * SCAN_B + tid;
    int v = (i < N) ? cnt[i] : 0;
    lds[tid] = v;
    __syncthreads();
    for (int o = 1; o < SCAN_B; o <<= 1) {
        int t = (tid >= o) ? lds[tid - o] : 0;
        __syncthreads();
        lds[tid] += t;
        __syncthreads();
    }
    if (i < N) rs[i] = lds[tid] - v;
    if (tid == SCAN_B - 1) bsum[blockIdx.x] = lds[tid];
}

__global__ void scan_pass2(int* __restrict__ bsum, int nb) {
    __shared__ int lds[SCAN_B];
    int tid = threadIdx.x;
    int v = (tid < nb) ? bsum[tid] : 0;
    lds[tid] = v;
    __syncthreads();
    for (int o = 1; o < SCAN_B; o <<= 1) {
        int t = (tid >= o) ? lds[tid - o] : 0;
        __syncthreads();
        lds[tid] += t;
        __syncthreads();
    }
    if (tid < nb) bsum[tid] = lds[tid] - v;
}

__global__ void scan_pass3(int* __restrict__ rs, int* __restrict__ cursor,
                           const int* __restrict__ bsum, const int* __restrict__ cnt,
                           float* __restrict__ inv, int N) {
    int i = blockIdx.x * SCAN_B + threadIdx.x;
    if (i < N) {
        int v = rs[i] + bsum[blockIdx.x];
        rs[i] = v;
        cursor[i] = v;
        inv[i] = 1.0f / (float)max(cnt[i], 1);
    }
}

__global__ void fill_kernel(const int* __restrict__ ei, int E,
                            int* __restrict__ cursor, int* __restrict__ csr) {
    int e = blockIdx.x * blockDim.x + threadIdx.x;
    if (e < E) {
        int src = ei[e], dst = ei[E + e];
        int pos = atomicAdd(&cursor[dst], 1);
        csr[pos] = src;
    }
}

// ---- gather-mean aggregate: 32 lanes per node, 8-way unrolled ----
__global__ void aggregate_kernel(const float* __restrict__ x, const int* __restrict__ csr,
                                 const int* __restrict__ rs, const int* __restrict__ cnt,
                                 const float* __restrict__ inv, float* __restrict__ agg,
                                 int N) {
    int t = blockIdx.x * blockDim.x + threadIdx.x;
    int node = t >> 5;
    int c = t & 31;
    if (node >= N) return;
    int deg = cnt[node];
    int st = rs[node];
    const float4* x4 = (const float4*)x;
    float4 s0 = make_float4(0.f, 0.f, 0.f, 0.f);
    float4 s1 = make_float4(0.f, 0.f, 0.f, 0.f);
    int i = 0;
    for (; i + 8 <= deg; i += 8) {
        int n0 = csr[st + i + 0], n1 = csr[st + i + 1];
        int n2 = csr[st + i + 2], n3 = csr[st + i + 3];
        int n4 = csr[st + i + 4], n5 = csr[st + i + 5];
        int n6 = csr[st + i + 6], n7 = csr[st + i + 7];
        float4 v0 = x4[(size_t)n0 * 32 + c];
        float4 v1 = x4[(size_t)n1 * 32 + c];
        float4 v2 = x4[(size_t)n2 * 32 + c];
        float4 v3 = x4[(size_t)n3 * 32 + c];
        float4 v4 = x4[(size_t)n4 * 32 + c];
        float4 v5 = x4[(size_t)n5 * 32 + c];
        float4 v6 = x4[(size_t)n6 * 32 + c];
        float4 v7 = x4[(size_t)n7 * 32 + c];
        s0.x += (v0.x + v1.x) + (v2.x + v3.x);
        s0.y += (v0.y + v1.y) + (v2.y + v3.y);
        s0.z += (v0.z + v1.z) + (v2.z + v3.z);
        s0.w += (v0.w + v1.w) + (v2.w + v3.w);
        s1.x += (v4.x + v5.x) + (v6.x + v7.x);
        s1.y += (v4.y + v5.y) + (v6.y + v7.y);
        s1.z += (v4.z + v5.z) + (v6.z + v7.z);
        s1.w += (v4.w + v5.w) + (v6.w + v7.w);
    }
    for (; i + 4 <= deg; i += 4) {
        int n0 = csr[st + i + 0], n1 = csr[st + i + 1];
        int n2 = csr[st + i + 2], n3 = csr[st + i + 3];
        float4 v0 = x4[(size_t)n0 * 32 + c];
        float4 v1 = x4[(size_t)n1 * 32 + c];
        float4 v2 = x4[(size_t)n2 * 32 + c];
        float4 v3 = x4[(size_t)n3 * 32 + c];
        s0.x += v0.x + v1.x; s0.y += v0.y + v1.y;
        s0.z += v0.z + v1.z; s0.w += v0.w + v1.w;
        s1.x += v2.x + v3.x; s1.y += v2.y + v3.y;
        s1.z += v2.z + v3.z; s1.w += v2.w + v3.w;
    }
    for (; i < deg; i++) {
        int n0 = csr[st + i];
        float4 v0 = x4[(size_t)n0 * 32 + c];
        s0.x += v0.x; s0.y += v0.y; s0.z += v0.z; s0.w += v0.w;
    }
    float iv = inv[node];
    float4 s = make_float4((s0.x + s1.x) * iv, (s0.y + s1.y) * iv,
                           (s0.z + s1.z) * iv, (s0.w + s1.w) * iv);
    ((float4*)agg)[(size_t)node * 32 + c] = s;
}

// ---- weight pack: fp32 [128k x 128n] -> bf16 hi/lo fragment-ordered ----
// element (ks, t, lane, j) = W[ks*32 + (lane>>4)*8 + j][t*16 + (lane&15)]
// 5 matrices x 2048 threads; hi at pw + w*32768, lo at +16384.
__global__ void pack_kernel(const float* __restrict__ W1l, const float* __restrict__ W1r,
                            const float* __restrict__ W2l, const float* __restrict__ W2r,
                            const float* __restrict__ Wf, unsigned short* __restrict__ pw) {
    int idx = blockIdx.x * blockDim.x + threadIdx.x;
    if (idx >= 5 * 2048) return;
    int w = idx >> 11;
    int r = idx & 2047;
    int ks = r >> 9;
    int t = (r >> 6) & 7;
    int lane = r & 63;
    int q = lane >> 4, n = lane & 15;
    const float* W = (w == 0) ? W1l : (w == 1) ? W1r : (w == 2) ? W2l : (w == 3) ? W2r : Wf;
    unsigned short* dh = pw + (size_t)w * 32768;
    unsigned short* dl = dh + 16384;
    int off = ((ks * 8 + t) * 64 + lane) * 8;
#pragma unroll
    for (int j = 0; j < 8; j++) {
        float v = W[(size_t)(ks * 32 + q * 8 + j) * D + t * 16 + n];
        unsigned short hb = f2bf(v);
        dh[off + j] = hb;
        dl[off + j] = f2bf(v - bf2f(hb));
    }
}

// ---- MFMA split-bf16 fused GEMM ----
// block: 256 thr = 4 waves; BM=64 (16 rows/wave); BN=128 (8 tiles of 16); K=256.
// C = relu(l2norm([agg|x] @ [Wl;Wr] + bl)) [@ Wf + bf]
template <int FUSE_FC>
__global__ __launch_bounds__(256) void mfma_gemm(
        const float* __restrict__ Aagg, const float* __restrict__ Ax,
        const unsigned short* __restrict__ W0h, const unsigned short* __restrict__ W0lo,
        const unsigned short* __restrict__ W1h, const unsigned short* __restrict__ W1lo,
        const float* __restrict__ bias,
        const unsigned short* __restrict__ Wfh, const unsigned short* __restrict__ Wflo,
        const float* __restrict__ bfin,
        float* __restrict__ out, int N) {
    __shared__ float As[64 * AS_LD];                               // 9216 B
    __shared__ unsigned short Hs[FUSE_FC ? 4 * 4096 : 4];          // 32 KB (FC)

    const int tid = threadIdx.x;
    const int lane = tid & 63;
    const int wave = tid >> 6;
    const int c = lane & 15;   // C col within tile / A row m
    const int q = lane >> 4;   // quad
    const int mb = blockIdx.x * 64;
    const int wm = wave * 16;

    f32x4 acc[8];
#pragma unroll
    for (int t = 0; t < 8; t++)
#pragma unroll
        for (int r = 0; r < 4; r++) acc[t][r] = 0.0f;

    for (int ks = 0; ks < 8; ks++) {
        const float* Asrc = (ks < 4) ? Aagg : Ax;
        const int kl = ks & 3;
        // stage 64x32 fp32 A tile (coalesced float4)
#pragma unroll
        for (int rp = 0; rp < 2; rp++) {
            int f = tid + rp * 256;
            int m = f >> 3, kq = f & 7;
            int g = mb + m;
            if (g >= N) g = N - 1;
            float4 v = ((const float4*)Asrc)[(size_t)g * 32 + kl * 8 + kq];
            *((float4*)&As[m * AS_LD + kq * 4]) = v;
        }
        __syncthreads();

        // A fragment: A[m = c][k = q*8 + j], split hi/lo
        const float* ap = &As[(wm + c) * AS_LD + q * 8];
        float4 a0 = *((const float4*)ap);
        float4 a1 = *((const float4*)(ap + 4));
        float av[8] = {a0.x, a0.y, a0.z, a0.w, a1.x, a1.y, a1.z, a1.w};
        bf16x8 ah, alo;
#pragma unroll
        for (int j = 0; j < 8; j++) {
            unsigned short hb = f2bf(av[j]);
            ah[j] = (short)hb;
            alo[j] = (short)f2bf(av[j] - bf2f(hb));
        }

        const uint4* Wh4 = (const uint4*)((ks < 4) ? W0h : W1h);
        const uint4* Wl4 = (const uint4*)((ks < 4) ? W0lo : W1lo);
#pragma unroll
        for (int t = 0; t < 8; t++) {
            int fi = (kl * 8 + t) * 64 + lane;
            bf16x8 bh = __builtin_bit_cast(bf16x8, Wh4[fi]);
            bf16x8 blo = __builtin_bit_cast(bf16x8, Wl4[fi]);
            acc[t] = __builtin_amdgcn_mfma_f32_16x16x32_bf16(ah, bh, acc[t], 0, 0, 0);
            acc[t] = __builtin_amdgcn_mfma_f32_16x16x32_bf16(alo, bh, acc[t], 0, 0, 0);
            acc[t] = __builtin_amdgcn_mfma_f32_16x16x32_bf16(ah, blo, acc[t], 0, 0, 0);
        }
        __syncthreads();
    }

    // epilogue: bias + per-row L2 norm + relu  (C layout: col=c+16t, row=q*4+r)
#pragma unroll
    for (int t = 0; t < 8; t++) {
        float bv = bias[t * 16 + c];
#pragma unroll
        for (int r = 0; r < 4; r++) acc[t][r] += bv;
    }
    float s[4];
#pragma unroll
    for (int r = 0; r < 4; r++) {
        float v = 0.0f;
#pragma unroll
        for (int t = 0; t < 8; t++) v += acc[t][r] * acc[t][r];
        v += __shfl_xor(v, 1, 16);
        v += __shfl_xor(v, 2, 16);
        v += __shfl_xor(v, 4, 16);
        v += __shfl_xor(v, 8, 16);
        s[r] = 1.0f / fmaxf(sqrtf(v), 1e-12f);
    }
#pragma unroll
    for (int t = 0; t < 8; t++)
#pragma unroll
        for (int r = 0; r < 4; r++) acc[t][r] = fmaxf(acc[t][r] * s[r], 0.0f);

    if (!FUSE_FC) {
#pragma unroll
        for (int t = 0; t < 8; t++)
#pragma unroll
            for (int r = 0; r < 4; r++) {
                int row = mb + wm + q * 4 + r;
                if (row < N) out[(size_t)row * D + t * 16 + c] = acc[t][r];
            }
        return;
    }

    // pack h into per-wave LDS, A-operand fragment order, bf16 hi/lo
    unsigned short* Hw = &Hs[wave * 4096];
#pragma unroll
    for (int t = 0; t < 8; t++)
#pragma unroll
        for (int r = 0; r < 4; r++) {
            int row = q * 4 + r;
            int col = t * 16 + c;
            int ks2 = col >> 5, c32 = col & 31;
            int off = ((ks2 * 64) + (c32 >> 3) * 16 + row) * 8 + (c32 & 7);
            float hv = acc[t][r];
            unsigned short hb = f2bf(hv);
            Hw[off] = hb;
            Hw[2048 + off] = f2bf(hv - bf2f(hb));
        }
    __syncthreads();

    f32x4 acc2[8];
#pragma unroll
    for (int t = 0; t < 8; t++) {
        float bv = bfin[t * 16 + c];
#pragma unroll
        for (int r = 0; r < 4; r++) acc2[t][r] = bv;
    }
    const uint4* Wfh4 = (const uint4*)Wfh;
    const uint4* Wfl4 = (const uint4*)Wflo;
#pragma unroll
    for (int ks2 = 0; ks2 < 4; ks2++) {
        bf16x8 ah2 = __builtin_bit_cast(bf16x8, ((const uint4*)Hw)[ks2 * 64 + lane]);
        bf16x8 al2 = __builtin_bit_cast(bf16x8, ((const uint4*)(Hw + 2048))[ks2 * 64 + lane]);
#pragma unroll
        for (int t = 0; t < 8; t++) {
            int fi = (ks2 * 8 + t) * 64 + lane;
            bf16x8 bh = __builtin_bit_cast(bf16x8, Wfh4[fi]);
            bf16x8 blo = __builtin_bit_cast(bf16x8, Wfl4[fi]);
            acc2[t] = __builtin_amdgcn_mfma_f32_16x16x32_bf16(ah2, bh, acc2[t], 0, 0, 0);
            acc2[t] = __builtin_amdgcn_mfma_f32_16x16x32_bf16(al2, bh, acc2[t], 0, 0, 0);
            acc2[t] = __builtin_amdgcn_mfma_f32_16x16x32_bf16(ah2, blo, acc2[t], 0, 0, 0);
        }
    }

#pragma unroll
    for (int t = 0; t < 8; t++)
#pragma unroll
        for (int r = 0; r < 4; r++) {
            int row = mb + wm + q * 4 + r;
            if (row < N) out[(size_t)row * D + t * 16 + c] = acc2[t][r];
        }
}

extern "C" void kernel_launch(void* const* d_in, const int* in_sizes, int n_in,
                              void* d_out, int out_size, void* d_ws, size_t ws_size,
                              hipStream_t stream) {
    const float* x   = (const float*)d_in[0];
    const int*   ei  = (const int*)d_in[1];
    const float* W1l = (const float*)d_in[2];
    const float* b1  = (const float*)d_in[3];
    const float* W1r = (const float*)d_in[4];
    const float* W2l = (const float*)d_in[5];
    const float* b2  = (const float*)d_in[6];
    const float* W2r = (const float*)d_in[7];
    const float* Wf  = (const float*)d_in[8];
    const float* bf  = (const float*)d_in[9];
    float* out = (float*)d_out;

    int N = in_sizes[0] / D;
    int E = in_sizes[1] / 2;

    // ws: agg[N*D] f | inv[N] f | rs[N] i | cnt[N] i | cursor[N] i | bsum[256] i | csr[E] i | packW
    float* ws     = (float*)d_ws;
    float* agg    = ws;
    float* inv    = ws + (size_t)N * D;
    int*   rs     = (int*)(inv + N);
    int*   cnt    = rs + N;
    int*   cursor = cnt + N;
    int*   bsum   = cursor + N;
    int*   csr    = bsum + 256;
    unsigned short* pw = (unsigned short*)(csr + E);
    // packed layout: matrix w in {W1l,W1r,W2l,W2r,Wf}: hi = pw + w*32768, lo = hi + 16384
    unsigned short* pW1lh = pw + 0 * 32768, *pW1ll = pW1lh + 16384;
    unsigned short* pW1rh = pw + 1 * 32768, *pW1rl = pW1rh + 16384;
    unsigned short* pW2lh = pw + 2 * 32768, *pW2ll = pW2lh + 16384;
    unsigned short* pW2rh = pw + 3 * 32768, *pW2rl = pW2rh + 16384;
    unsigned short* pWfh  = pw + 4 * 32768, *pWfl  = pWfh + 16384;

    int nb = (N + SCAN_B - 1) / SCAN_B;

    hipMemsetAsync(cnt, 0, (size_t)N * sizeof(int), stream);
    pack_kernel<<<40, 256, 0, stream>>>(W1l, W1r, W2l, W2r, Wf, pw);
    count_kernel<<<(E + 255) / 256, 256, 0, stream>>>(ei, E, cnt);
    scan_pass1<<<nb, SCAN_B, 0, stream>>>(cnt, rs, bsum, N);
    scan_pass2<<<1, SCAN_B, 0, stream>>>(bsum, nb);
    scan_pass3<<<nb, SCAN_B, 0, stream>>>(rs, cursor, bsum, cnt, inv, N);
    fill_kernel<<<(E + 255) / 256, 256, 0, stream>>>(ei, E, cursor, csr);

    int agg_blocks = (N * 32 + 255) / 256;
    int gemm_blocks = (N + 63) / 64;

    // layer 1 (h1 lives in d_out)
    aggregate_kernel<<<agg_blocks, 256, 0, stream>>>(x, csr, rs, cnt, inv, agg, N);
    mfma_gemm<0><<<gemm_blocks, 256, 0, stream>>>(agg, x, pW1lh, pW1ll, pW1rh, pW1rl, b1,
                                                  nullptr, nullptr, nullptr, out, N);

    // layer 2 + fused FC (reads h1 from d_out, overwrites d_out; row-aligned, no cross-block alias)
    aggregate_kernel<<<agg_blocks, 256, 0, stream>>>(out, csr, rs, cnt, inv, agg, N);
    mfma_gemm<1><<<gemm_blocks, 256, 0, stream>>>(agg, out, pW2lh, pW2ll, pW2rh, pW2rl, b2,
                                                  pWfh, pWfl, bf, out, N);
}